// Round 11
// baseline (114.308 us; speedup 1.0000x reference)
//
#include <hip/hip_runtime.h>

#define N_NODES 10000
#define N_EDGES 640000
#define D 128
#define NQ (N_EDGES / 4)      // 160000 edge quads

#define NSCAT 512             // scatter blocks (no LDS use)
#define GEMM_BLOCKS 157       // 64 nodes per block (MFMA)
#define GRID1 (NSCAT + GEMM_BLOCKS)   // 669 blocks, all co-resident (4/CU cap)
#define REGCAP 112            // per-row cap: mean 64, +6 sigma (P(>112)~1e-8)
#define RSTRIDE 128           // uint32 slots per row strip (512B, 8 lines)
#define CSTRIDE 16            // cursor stride in ints (64B: one line per row)
#define SPILLCAP 4096         // global spill list
#define CAP2 128              // gather fast-path cap
#define QPAD2 144             // CAP2 + 16 zero-pad
#define LSTR 136              // LDS row stride in ushorts (272B)

typedef unsigned int uint32;
typedef unsigned long long u64;
typedef unsigned short u16;
using short8 = __attribute__((ext_vector_type(8))) short;
using f32x4  = __attribute__((ext_vector_type(4))) float;

__device__ __forceinline__ uint32 f2bf_bits(float f) {
    uint32 u = __float_as_uint(f);
    return (u + 0x7FFFu + ((u >> 16) & 1u)) >> 16;   // RNE bf16 bits
}
__device__ __forceinline__ uint32 pack2(float lo, float hi) {
    return f2bf_bits(lo) | (f2bf_bits(hi) << 16);
}

// R19: ledger (R17-calibrated) shows k1 ~= 42us and k1 tracks DISTINCT
// 64B-LINE TOUCHES of its scattered stores (R12 121K->17us, R13 160K->22us,
// R15-18 560K->42us), not op count (R18 concurrency null, R11 atomics null).
// Fix: dense per-row strips. pos = atomicAdd(cursor[row]) (global atomics
// proven ~free in R10/R11); region[row][pos] is a dense 512B strip => ~80K
// line touches, 5MB L2-resident footprint. k2's queue build collapses to a
// count read + one coalesced uint2 strip load (no compaction). Costs one
// 640KB memset dispatch. Scatter blocks use no LDS => 512 of them.
__global__ __launch_bounds__(256, 4) void gemm_scatter_kernel(
    const float* __restrict__ x, const float* __restrict__ w,
    const int* __restrict__ row, const int* __restrict__ col,
    const float* __restrict__ val,
    uint32* __restrict__ h2, int* __restrict__ cursor,
    int* __restrict__ spillcnt, uint32* __restrict__ region,
    uint2* __restrict__ spill)
{
    __shared__ __align__(16) u16 Ws[128 * LSTR];   // 34816 B (GEMM only)
    const int t = threadIdx.x;

    if (blockIdx.x < NSCAT) {
        // ---- scatter: 1-2 quads/thread, dense per-row placement ----
        const int tid = blockIdx.x * 256 + t;
        const int stride = NSCAT * 256;
        const int4*   row4 = (const int4*)row;
        const int4*   col4 = (const int4*)col;
        const float4* val4 = (const float4*)val;
        for (int i = tid; i < NQ; i += stride) {
            int4 r = row4[i]; int4 c = col4[i]; float4 v = val4[i];
            #pragma unroll
            for (int e = 0; e < 4; ++e) {
                int rr = (e == 0) ? r.x : (e == 1) ? r.y : (e == 2) ? r.z : r.w;
                int cc = (e == 0) ? c.x : (e == 1) ? c.y : (e == 2) ? c.z : c.w;
                float vv = (e == 0) ? v.x : (e == 1) ? v.y : (e == 2) ? v.z : v.w;
                uint32 rc = (uint32)cc | (f2bf_bits(vv) << 16);
                int pos = atomicAdd(&cursor[rr * CSTRIDE], 1);
                if (pos < REGCAP)
                    region[(size_t)rr * RSTRIDE + pos] = rc;  // dense strip
                else {                                        // +6 sigma, ~never
                    int o = atomicAdd(spillcnt, 1);
                    if (o < SPILLCAP) spill[o] = make_uint2((uint32)rr, rc);
                }
            }
        }
    } else {
        // ---- MFMA GEMM: 64 rows/block, 4 waves x 16 rows x 128 cols.
        // A direct global->reg; W staged col-major in LDS (float4 loads).
        // C/D: col=lane&15, row=quad*4+reg (HW-verified).
        const int g = blockIdx.x - NSCAT;
        const int lane = t & 63;
        const int wid  = t >> 6;
        const int q = lane >> 4, cl = lane & 15;

        const float4* w4 = (const float4*)w;
        #pragma unroll
        for (int i = 0; i < 8; ++i) {                 // stage W^T (128x128)
            int lin = t + i * 256;                    // m(k-pair) x qc(col-quad)
            int m  = lin >> 5;
            int qc = lin & 31;
            float4 r0 = w4[(2 * m) * 32 + qc];        // row 2m, cols 4qc..4qc+3
            float4 r1 = w4[(2 * m + 1) * 32 + qc];
            int c = qc * 4;
            *(uint32*)&Ws[(c + 0) * LSTR + 2 * m] = pack2(r0.x, r1.x);
            *(uint32*)&Ws[(c + 1) * LSTR + 2 * m] = pack2(r0.y, r1.y);
            *(uint32*)&Ws[(c + 2) * LSTR + 2 * m] = pack2(r0.z, r1.z);
            *(uint32*)&Ws[(c + 3) * LSTR + 2 * m] = pack2(r0.w, r1.w);
        }

        int gr = g * 64 + wid * 16 + cl;              // A-fragment row
        if (gr >= N_NODES) gr = N_NODES - 1;          // tail clamp (guarded write)
        const float* xrow = &x[(size_t)gr * D];
        float4 xv[8];
        #pragma unroll
        for (int kk = 0; kk < 4; ++kk) {
            xv[2 * kk]     = *(const float4*)&xrow[kk * 32 + q * 8];
            xv[2 * kk + 1] = *(const float4*)&xrow[kk * 32 + q * 8 + 4];
        }
        __syncthreads();

        f32x4 acc[8] = {};
        #pragma unroll
        for (int kk = 0; kk < 4; ++kk) {
            union { short8 s; uint32 u[4]; } af;
            float4 a = xv[2 * kk], b = xv[2 * kk + 1];
            af.u[0] = pack2(a.x, a.y); af.u[1] = pack2(a.z, a.w);
            af.u[2] = pack2(b.x, b.y); af.u[3] = pack2(b.z, b.w);
            #pragma unroll
            for (int ct = 0; ct < 8; ++ct) {
                short8 bf = *(const short8*)&Ws[(ct * 16 + cl) * LSTR + kk * 32 + q * 8];
                acc[ct] = __builtin_amdgcn_mfma_f32_16x16x32_bf16(af.s, bf, acc[ct], 0, 0, 0);
            }
        }
        #pragma unroll
        for (int reg = 0; reg < 4; ++reg) {
            int node = g * 64 + wid * 16 + q * 4 + reg;
            if (node < N_NODES) {
                uint32* base = h2 + (size_t)node * 64 + cl;
                #pragma unroll
                for (int ct = 0; ct < 4; ++ct)
                    base[ct * 16] = pack2(acc[ct][reg], acc[ct + 4][reg]);
            }
        }
    }
}

// k2: 8 rows/block (1250 blocks), wave w owns rows (2w, 2w+1) sequentially.
// Queue build: count from cursor (t<8 scalar loads -> LDS), one coalesced
// uint2 strip load per row (512B), predicated LDS writes. Gather: proven
// branch-free depth-8 software-pipelined loop (8 L2 gathers in flight).
__global__ __launch_bounds__(256) void spmm_kernel(
    const uint32* __restrict__ region, const int* __restrict__ cursor,
    const int* __restrict__ spillcnt, const uint2* __restrict__ spill,
    const uint32* __restrict__ h2, const float* __restrict__ bias,
    float* __restrict__ out)
{
    __shared__ uint32 qbuf[8 * QPAD2];    // per-(wave,half) queues (4608 B)
    __shared__ int cnt8[8];
    const int t = threadIdx.x;
    const int lane = t & 63;
    const int wid  = t >> 6;
    const int r0 = blockIdx.x * 8;

    if (t < 8) {
        int c = cursor[(r0 + t) * CSTRIDE];
        cnt8[t] = (c < REGCAP) ? c : REGCAP;
    }
    int nsp = spillcnt[0];                 // hot line, broadcast
    if (nsp > SPILLCAP) nsp = SPILLCAP;
    __syncthreads();

    for (int half = 0; half < 2; ++half) {
        const int d = wid * 2 + half;
        const int r = r0 + d;
        uint32* qp = &qbuf[d * QPAD2];
        int cnt = cnt8[d];

        // one coalesced 512B strip load: lane holds recs (2*lane, 2*lane+1)
        uint2 rv = *(const uint2*)&region[(size_t)r * RSTRIDE + 2 * lane];
        if (2 * lane     < cnt) qp[2 * lane]     = rv.x;
        if (2 * lane + 1 < cnt) qp[2 * lane + 1] = rv.y;
        int ntot = cnt;

        if (nsp > 0) {                                    // ~never taken
            for (int k = 0; k < nsp; ++k) {
                uint2 e = spill[k];
                if (e.x == (uint32)r) {
                    if (lane == 0 && ntot < CAP2) qp[ntot] = e.y;
                    ntot++;
                }
            }
        }

        float a0 = 0.f, a1 = 0.f;
        if (ntot <= CAP2) {
            if (lane < 16) qp[ntot + lane] = 0;    // zero pad (val=+0.0 recs)
            __builtin_amdgcn_s_waitcnt(0);         // wave-local LDS drain

            const int npad = (ntot + 7) & ~7;
            uint32 rq0,rq1,rq2,rq3,rq4,rq5,rq6,rq7;
            uint32 hh0,hh1,hh2,hh3,hh4,hh5,hh6,hh7;
            rq0 = qp[0]; hh0 = h2[((rq0 & 0xFFFFu) << 6) + lane];
            rq1 = qp[1]; hh1 = h2[((rq1 & 0xFFFFu) << 6) + lane];
            rq2 = qp[2]; hh2 = h2[((rq2 & 0xFFFFu) << 6) + lane];
            rq3 = qp[3]; hh3 = h2[((rq3 & 0xFFFFu) << 6) + lane];
            rq4 = qp[4]; hh4 = h2[((rq4 & 0xFFFFu) << 6) + lane];
            rq5 = qp[5]; hh5 = h2[((rq5 & 0xFFFFu) << 6) + lane];
            rq6 = qp[6]; hh6 = h2[((rq6 & 0xFFFFu) << 6) + lane];
            rq7 = qp[7]; hh7 = h2[((rq7 & 0xFFFFu) << 6) + lane];

#define CONSUME_PREFETCH(RQ, HH, P)                                          \
    {                                                                        \
        a0 = fmaf(__uint_as_float(RQ & 0xFFFF0000u),                         \
                  __uint_as_float(HH << 16), a0);                            \
        a1 = fmaf(__uint_as_float(RQ & 0xFFFF0000u),                         \
                  __uint_as_float(HH & 0xFFFF0000u), a1);                    \
        uint32 rn = qp[j + 8 + P];                                           \
        RQ = rn; HH = h2[((rn & 0xFFFFu) << 6) + lane];                      \
    }

            for (int j = 0; j < npad; j += 8) {
                CONSUME_PREFETCH(rq0, hh0, 0)
                CONSUME_PREFETCH(rq1, hh1, 1)
                CONSUME_PREFETCH(rq2, hh2, 2)
                CONSUME_PREFETCH(rq3, hh3, 3)
                CONSUME_PREFETCH(rq4, hh4, 4)
                CONSUME_PREFETCH(rq5, hh5, 5)
                CONSUME_PREFETCH(rq6, hh6, 6)
                CONSUME_PREFETCH(rq7, hh7, 7)
            }
#undef CONSUME_PREFETCH
        } else {
            // slow path (row deg > CAP2; ~never): broadcast-scan strip + spills.
            for (int k = 0; k < cnt; ++k) {
                uint32 rec = region[(size_t)r * RSTRIDE + k];
                uint32 hv = h2[((rec & 0xFFFFu) << 6) + lane];
                a0 = fmaf(__uint_as_float(rec & 0xFFFF0000u),
                          __uint_as_float(hv << 16), a0);
                a1 = fmaf(__uint_as_float(rec & 0xFFFF0000u),
                          __uint_as_float(hv & 0xFFFF0000u), a1);
            }
            for (int k = 0; k < nsp; ++k) {
                uint2 e = spill[k];
                if (e.x == (uint32)r) {
                    uint32 hv = h2[((e.y & 0xFFFFu) << 6) + lane];
                    a0 = fmaf(__uint_as_float(e.y & 0xFFFF0000u),
                              __uint_as_float(hv << 16), a0);
                    a1 = fmaf(__uint_as_float(e.y & 0xFFFF0000u),
                              __uint_as_float(hv & 0xFFFF0000u), a1);
                }
            }
        }

        out[(size_t)r * D + lane]      = a0 + bias[lane];
        out[(size_t)r * D + 64 + lane] = a1 + bias[lane + 64];
    }
}

extern "C" void kernel_launch(void* const* d_in, const int* in_sizes, int n_in,
                              void* d_out, int out_size, void* d_ws, size_t ws_size,
                              hipStream_t stream)
{
    const float* x    = (const float*)d_in[0];
    const float* aval = (const float*)d_in[1];
    const float* w    = (const float*)d_in[2];
    const float* bias = (const float*)d_in[3];
    const int* arow   = (const int*)d_in[4];
    const int* acol   = (const int*)d_in[5];

    char* ws = (char*)d_ws;
    uint32* h2       = (uint32*)(ws);              //  2,560,000 B
    int*    cursor   = (int*)(ws + 2560000);       //    640,000 B (10000 x 64B)
    int*    spillcnt = (int*)(ws + 3200000);       //         64 B
    uint2*  spill    = (uint2*)(ws + 3200064);     //     32,768 B (4096 x 8)
    uint32* region   = (uint32*)(ws + 3232832);    //  5,120,000 B (10000 x 512B)
    // total 8,352,832 B; memset covers cursor + spillcnt only (640,064 B).

    hipMemsetAsync(ws + 2560000, 0, 640064, stream);

    gemm_scatter_kernel<<<GRID1, 256, 0, stream>>>(
        x, w, arow, acol, aval, h2, cursor, spillcnt, region, spill);
    spmm_kernel<<<N_NODES / 8, 256, 0, stream>>>(
        region, cursor, spillcnt, spill, h2, bias, (float*)d_out);
}